// Round 11
// baseline (258.850 us; speedup 1.0000x reference)
//
#include <hip/hip_runtime.h>
#include <cstdint>
#include <cstddef>

#define I_DIM 4096
#define O_DIM 4096
#define RNK 32
#define NGRP 64
#define N_TOK 4096

typedef int v4i  __attribute__((ext_vector_type(4)));
typedef int v16i __attribute__((ext_vector_type(16)));

__device__ __forceinline__ int clamp_i8(float v) {
    int q = (int)rintf(v);           // round half to even, matches jnp.round
    q = q < -128 ? -128 : q;
    q = q > 127 ? 127 : q;
    return q;
}

// ---------------------------------------------------------------------------
// prep_kernel = quant_w (blocks [0,1024)) + quant_x (blocks [1024,5120)).
// ---------------------------------------------------------------------------
#define BO 4
#define W_BLOCKS (O_DIM / BO)   // 1024

__device__ __forceinline__ void quant_w_body(
    const int* __restrict__ w_packed, const float* __restrict__ svd_up,
    const float* __restrict__ svd_down, const float* __restrict__ scale,
    const float* __restrict__ zp, char* __restrict__ w_q,
    float* __restrict__ scale_w, int blk)
{
    __shared__ float s_sc[BO][NGRP];
    __shared__ float s_zp[BO][NGRP];
    __shared__ float s_red[BO][4];
    __shared__ float s_sw[BO];

    const int tid = threadIdx.x;
    const int o0 = blk * BO;

    for (int t = tid; t < BO * NGRP; t += 256) {
        s_sc[t >> 6][t & 63] = scale[(size_t)(o0 + (t >> 6)) * NGRP + (t & 63)];
        s_zp[t >> 6][t & 63] = zp[(size_t)(o0 + (t >> 6)) * NGRP + (t & 63)];
    }
    __syncthreads();

    float W[4][BO][4];     // [col-quad jq][row ro][col-in-quad]

    // affine dequant of the int4 values (init)
#pragma unroll
    for (int jq = 0; jq < 4; jq++) {
        const int q = tid + 256 * jq;    // col-quad index, 0..1023
        const int g = q >> 4;            // group (4 cols same group)
#pragma unroll
        for (int ro = 0; ro < BO; ro++) {
            const int2 b2 = *(const int2*)&w_packed[(size_t)(o0 + ro) * (I_DIM / 2) + 2 * q];
            const float sc = s_sc[ro][g], z = s_zp[ro][g];
            W[jq][ro][0] = ((float)(b2.x & 0xF) - z) * sc;
            W[jq][ro][1] = ((float)((b2.x >> 4) & 0xF) - z) * sc;
            W[jq][ro][2] = ((float)(b2.y & 0xF) - z) * sc;
            W[jq][ro][3] = ((float)((b2.y >> 4) & 0xF) - z) * sc;
        }
    }

    // rank-32 SVD correction, r-OUTER; per-element accumulation order is
    // identical to the r-loop order -> bitwise-identical result.
#pragma unroll 2
    for (int r = 0; r < RNK; r++) {
        float u[BO];
#pragma unroll
        for (int ro = 0; ro < BO; ro++)
            u[ro] = svd_up[(size_t)(o0 + ro) * RNK + r];
        float4 d[4];
#pragma unroll
        for (int jq = 0; jq < 4; jq++)
            d[jq] = *(const float4*)&svd_down[(size_t)r * I_DIM + 4 * (tid + 256 * jq)];
#pragma unroll
        for (int jq = 0; jq < 4; jq++)
#pragma unroll
            for (int ro = 0; ro < BO; ro++) {
                W[jq][ro][0] += u[ro] * d[jq].x;
                W[jq][ro][1] += u[ro] * d[jq].y;
                W[jq][ro][2] += u[ro] * d[jq].z;
                W[jq][ro][3] += u[ro] * d[jq].w;
            }
    }

    float vmax[BO];
#pragma unroll
    for (int ro = 0; ro < BO; ro++) vmax[ro] = 0.0f;
#pragma unroll
    for (int jq = 0; jq < 4; jq++)
#pragma unroll
        for (int ro = 0; ro < BO; ro++)
            vmax[ro] = fmaxf(vmax[ro],
                fmaxf(fmaxf(fabsf(W[jq][ro][0]), fabsf(W[jq][ro][1])),
                      fmaxf(fabsf(W[jq][ro][2]), fabsf(W[jq][ro][3]))));

    // block-wide max per row
    const int lane = tid & 63, wv = tid >> 6;
#pragma unroll
    for (int ro = 0; ro < BO; ro++) {
        float m = vmax[ro];
        for (int off = 32; off > 0; off >>= 1)
            m = fmaxf(m, __shfl_down(m, off, 64));
        if (lane == 0) s_red[ro][wv] = m;
    }
    __syncthreads();
    if (tid < BO) {
        const float m = fmaxf(fmaxf(s_red[tid][0], s_red[tid][1]),
                              fmaxf(s_red[tid][2], s_red[tid][3]));
        const float sw = m / 127.0f;
        scale_w[o0 + tid] = sw;
        s_sw[tid] = sw;
    }
    __syncthreads();

    float inv[BO];
#pragma unroll
    for (int ro = 0; ro < BO; ro++) inv[ro] = 1.0f / s_sw[ro];

    // quantize from registers, pack 4 int8 per int store
#pragma unroll
    for (int jq = 0; jq < 4; jq++) {
        const int q = tid + 256 * jq;
#pragma unroll
        for (int ro = 0; ro < BO; ro++) {
            const int q0 = clamp_i8(W[jq][ro][0] * inv[ro]);
            const int q1 = clamp_i8(W[jq][ro][1] * inv[ro]);
            const int q2 = clamp_i8(W[jq][ro][2] * inv[ro]);
            const int q3 = clamp_i8(W[jq][ro][3] * inv[ro]);
            ((int*)w_q)[(size_t)(o0 + ro) * (I_DIM / 4) + q] =
                (q0 & 0xFF) | ((q1 & 0xFF) << 8) | ((q2 & 0xFF) << 16) | ((q3 & 0xFF) << 24);
        }
    }
}

__device__ __forceinline__ void quant_x_body(
    const float* __restrict__ x, char* __restrict__ x_q,
    float* __restrict__ scale_x, int n)
{
    const int tid = threadIdx.x;
    const float4* xr = (const float4*)(x + (size_t)n * I_DIM);
    float4 v[4];
    float m = 0.0f;
#pragma unroll
    for (int j = 0; j < 4; j++) {
        v[j] = xr[tid + 256 * j];
        m = fmaxf(m, fmaxf(fmaxf(fabsf(v[j].x), fabsf(v[j].y)),
                           fmaxf(fabsf(v[j].z), fabsf(v[j].w))));
    }
    __shared__ float s_red[4];
    __shared__ float s_sx;
    for (int off = 32; off > 0; off >>= 1)
        m = fmaxf(m, __shfl_down(m, off, 64));
    if ((tid & 63) == 0) s_red[tid >> 6] = m;
    __syncthreads();
    if (tid == 0) {
        const float mm = fmaxf(fmaxf(s_red[0], s_red[1]),
                               fmaxf(s_red[2], s_red[3]));
        const float sx = mm / 127.0f;
        scale_x[n] = sx;
        s_sx = sx;
    }
    __syncthreads();
    const float sx = s_sx;
    int* outw = (int*)(x_q + (size_t)n * I_DIM);
#pragma unroll
    for (int j = 0; j < 4; j++) {
        const int q0 = clamp_i8(v[j].x / sx);
        const int q1 = clamp_i8(v[j].y / sx);
        const int q2 = clamp_i8(v[j].z / sx);
        const int q3 = clamp_i8(v[j].w / sx);
        outw[tid + 256 * j] =
            (q0 & 0xFF) | ((q1 & 0xFF) << 8) | ((q2 & 0xFF) << 16) | ((q3 & 0xFF) << 24);
    }
}

__global__ __launch_bounds__(256, 4) void prep_kernel(
    const int* __restrict__ w_packed, const float* __restrict__ svd_up,
    const float* __restrict__ svd_down, const float* __restrict__ scale,
    const float* __restrict__ zp, char* __restrict__ w_q,
    float* __restrict__ scale_w,
    const float* __restrict__ x, char* __restrict__ x_q,
    float* __restrict__ scale_x)
{
    if (blockIdx.x < W_BLOCKS)
        quant_w_body(w_packed, svd_up, svd_down, scale, zp, w_q, scale_w, blockIdx.x);
    else
        quant_x_body(x, x_q, scale_x, blockIdx.x - W_BLOCKS);
}

// ---------------------------------------------------------------------------
// Kernel 2: int8 GEMM, 256x256 tile, BK=64 bytes, mfma_i32_32x32x32_i8.
//
// Round-11: REG-STAGED staging + 8B-granule swizzle + ds_read_b64 pairs.
// Bank model (fits r4 +8cyc, r6 zero, r10 +24cyc): column-reads at 64B row
// stride get 1 bank bit from row parity + the bits the swizzle injects into
// the column offset. 16B granule = 2 injected bits -> 8 groups over 32 rows
// -> 4-way floor (r4). 8B granule = 3 bits -> a 16-consecutive-lane phase
// covers 16 distinct bank-pair starts = all 32 banks -> ZERO conflicts
// (r6 measured 0). 8B swizzle g -> g^((row>>1)&7) needs per-row half-swaps
// that 16B-atomic global_load_lds cannot produce -> stage via registers:
//   global_load_dwordx4 -> VGPR (4/thread/tile) -> 8x ds_write_b64 at
//   swizzled addresses (writes also conflict-free: 16 lanes -> 16 starts).
// Structural bonus: load completion is now a per-wave REGISTER dependency
// (compiler auto-waitcnt before ds_write), so the per-tile barrier carries
// only lgkmcnt(0) -- no vmcnt drain in the barrier path at all.
// Schedule: r4's (reg-double-buffered frags, ONE barrier/K-tile, 3 LDS
// buffers 96KB, prefetch distance 2, setprio, XCD swizzle). Loop unrolled
// x2 with two named staging reg sets (static indexing, rule #20).
// ---------------------------------------------------------------------------
#define TBM 256
#define TBN 256
#define TBK 64
#define NKT (I_DIM / TBK)   // 64 K-tiles

// read fragment set (AF,BF) for phase P from buffer base BUF.
// logical 16B chunk c16 = P*2+h -> granules G0=2*c16, G0+1, each read as
// ds_read_b64 at physical granule (G ^ ((row>>1)&7)) * 8.  [r6-verified]
#define READ_FRAGS(AF, BF, BUF, P) do {                                     \
    char* Ac_ = (BUF);                                                      \
    char* Bc_ = (BUF) + 16384;                                              \
    const int G0_ = ((P) * 2 + h) * 2;                                      \
    _Pragma("unroll")                                                       \
    for (int mt = 0; mt < 4; mt++) {                                        \
        const int row = wm * 128 + mt * 32 + l31;                           \
        const int ss = (row >> 1) & 7;                                      \
        const int2 lo = *(const int2*)(Ac_ + row * TBK + ((G0_ ^ ss) * 8)); \
        const int2 hi = *(const int2*)(Ac_ + row * TBK + (((G0_ + 1) ^ ss) * 8)); \
        AF[mt][0] = lo.x; AF[mt][1] = lo.y;                                 \
        AF[mt][2] = hi.x; AF[mt][3] = hi.y;                                 \
    }                                                                       \
    _Pragma("unroll")                                                       \
    for (int nt = 0; nt < 2; nt++) {                                        \
        const int row = wn * 64 + nt * 32 + l31;                            \
        const int ss = (row >> 1) & 7;                                      \
        const int2 lo = *(const int2*)(Bc_ + row * TBK + ((G0_ ^ ss) * 8)); \
        const int2 hi = *(const int2*)(Bc_ + row * TBK + (((G0_ + 1) ^ ss) * 8)); \
        BF[nt][0] = lo.x; BF[nt][1] = lo.y;                                 \
        BF[nt][2] = hi.x; BF[nt][3] = hi.y;                                 \
    }                                                                       \
} while (0)

#define MFMA_CLUSTER(AF, BF) do {                                           \
    __builtin_amdgcn_s_setprio(1);                                          \
    _Pragma("unroll")                                                       \
    for (int mt = 0; mt < 4; mt++)                                          \
        _Pragma("unroll")                                                   \
        for (int nt = 0; nt < 2; nt++)                                      \
            acc[mt][nt] = __builtin_amdgcn_mfma_i32_32x32x32_i8(            \
                AF[mt], BF[nt], acc[mt][nt], 0, 0, 0);                      \
    __builtin_amdgcn_s_setprio(0);                                          \
} while (0)

// load tile t (linear, coalesced) into a staging reg set
#define GLOAD(A0_, A1_, B0_, B1_, t) do {                                   \
    A0_ = *(const v4i*)(gA0 + (size_t)(t) * TBK);                           \
    A1_ = *(const v4i*)(gA1 + (size_t)(t) * TBK);                           \
    B0_ = *(const v4i*)(gB0 + (size_t)(t) * TBK);                           \
    B1_ = *(const v4i*)(gB1 + (size_t)(t) * TBK);                           \
} while (0)

// write a staging reg set into LDS buffer (8B-swizzled, 8x ds_write_b64)
#define DSWRITE(A0_, A1_, B0_, B1_, bufp) do {                              \
    char* Ab_ = (bufp); char* Bb_ = (bufp) + 16384;                         \
    int2 w_;                                                                \
    w_.x = A0_[0]; w_.y = A0_[1]; *(int2*)(Ab_ + wo00) = w_;                \
    w_.x = A0_[2]; w_.y = A0_[3]; *(int2*)(Ab_ + wo01) = w_;                \
    w_.x = A1_[0]; w_.y = A1_[1]; *(int2*)(Ab_ + wo10) = w_;                \
    w_.x = A1_[2]; w_.y = A1_[3]; *(int2*)(Ab_ + wo11) = w_;                \
    w_.x = B0_[0]; w_.y = B0_[1]; *(int2*)(Bb_ + wo00) = w_;                \
    w_.x = B0_[2]; w_.y = B0_[3]; *(int2*)(Bb_ + wo01) = w_;                \
    w_.x = B1_[0]; w_.y = B1_[1]; *(int2*)(Bb_ + wo10) = w_;                \
    w_.x = B1_[2]; w_.y = B1_[3]; *(int2*)(Bb_ + wo11) = w_;                \
} while (0)

// one K-tile: CUR set holds tile t+2's data; NXT receives tile t+3's loads.
#define BODY(t, CA0, CA1, CB0, CB1, NA0, NA1, NB0, NB1) do {                \
    char* bufc = lds + cb * 32768;                                          \
    if ((t) + 3 < NKT) GLOAD(NA0, NA1, NB0, NB1, (t) + 3);                  \
    READ_FRAGS(a1, b1, bufc, 1);                                            \
    MFMA_CLUSTER(a0, b0);                                                   \
    if ((t) + 2 < NKT) DSWRITE(CA0, CA1, CB0, CB1, lds + nb * 32768);       \
    if ((t) < NKT - 1) {                                                    \
        asm volatile("s_waitcnt lgkmcnt(0)" ::: "memory");                  \
        asm volatile("s_barrier" ::: "memory");                             \
        char* bufn = lds + ((cb == 2) ? 0 : cb + 1) * 32768;                \
        READ_FRAGS(a0, b0, bufn, 0);                                        \
    }                                                                       \
    MFMA_CLUSTER(a1, b1);                                                   \
    cb = (cb == 2) ? 0 : cb + 1;                                            \
    nb = (nb == 2) ? 0 : nb + 1;                                            \
} while (0)

__global__ __launch_bounds__(512, 2) void gemm_i8_kernel(
    const char* __restrict__ x_q, const char* __restrict__ w_q,
    const float* __restrict__ scale_x, const float* __restrict__ scale_w,
    const float* __restrict__ bias, float* __restrict__ out)
{
    __shared__ v4i smem4[3 * 2 * 1024];     // 3 bufs x {A 16KB, B 16KB} = 96 KB
    char* lds = (char*)smem4;

    const int tid = threadIdx.x;
    // XCD-aware swizzle: xcd = id&7 owns bn bands [xcd*2, xcd*2+2);
    // s&15 sweeps bm within the band (B tile L2-resident per XCD).
    const int id = blockIdx.x;
    const int xcd = id & 7;
    const int s = id >> 3;                  // 0..31
    const int bm0 = (s & 15) * TBM;
    const int bn0 = (xcd * 2 + (s >> 4)) * TBN;

    const int lane = tid & 63, wv = tid >> 6;
    const int wm = wv >> 2, wn = wv & 3;    // 2M x 4N waves, 128x64 each
    const int l31 = lane & 31, h = lane >> 5;

    // staging geometry: thread handles 16B chunks c0=tid, c1=tid+512
    const int c0 = tid, c1 = tid + 512;
    const int r0s = c0 >> 2, r1s = c1 >> 2;
    const char* gA0 = x_q + (size_t)(bm0 + r0s) * I_DIM + (c0 & 3) * 16;
    const char* gA1 = x_q + (size_t)(bm0 + r1s) * I_DIM + (c1 & 3) * 16;
    const char* gB0 = w_q + (size_t)(bn0 + r0s) * I_DIM + (c0 & 3) * 16;
    const char* gB1 = w_q + (size_t)(bn0 + r1s) * I_DIM + (c1 & 3) * 16;
    const int s0s = (r0s >> 1) & 7, s1s = (r1s >> 1) & 7;
    const int wo00 = r0s * TBK + ((2 * (c0 & 3)    ) ^ s0s) * 8;
    const int wo01 = r0s * TBK + ((2 * (c0 & 3) + 1) ^ s0s) * 8;
    const int wo10 = r1s * TBK + ((2 * (c1 & 3)    ) ^ s1s) * 8;
    const int wo11 = r1s * TBK + ((2 * (c1 & 3) + 1) ^ s1s) * 8;

    v16i acc[4][2];
#pragma unroll
    for (int mt = 0; mt < 4; mt++)
#pragma unroll
        for (int nt = 0; nt < 2; nt++)
            acc[mt][nt] = (v16i)(0);

    v4i a0[4], b0[2], a1[4], b1[2];         // frag double buffer (static idx)
    v4i sA0, sA1, sB0, sB1;                 // staging set S (even tiles' CUR)
    v4i tA0, tA1, tB0, tB1;                 // staging set T

    // prologue: t0 -> S -> buf0; t1 -> T -> buf1; t2 -> S (in flight)
    GLOAD(sA0, sA1, sB0, sB1, 0);
    GLOAD(tA0, tA1, tB0, tB1, 1);
    DSWRITE(sA0, sA1, sB0, sB1, lds + 0 * 32768);   // compiler waits t0 loads
    GLOAD(sA0, sA1, sB0, sB1, 2);
    DSWRITE(tA0, tA1, tB0, tB1, lds + 1 * 32768);   // compiler waits t1 loads
    asm volatile("s_waitcnt lgkmcnt(0)" ::: "memory");
    asm volatile("s_barrier" ::: "memory");
    READ_FRAGS(a0, b0, lds + 0 * 32768, 0);

    int cb = 0, nb = 2;
    for (int t = 0; t < NKT; t += 2) {
        BODY(t,     sA0, sA1, sB0, sB1, tA0, tA1, tB0, tB1);
        BODY(t + 1, tA0, tA1, tB0, tB1, sA0, sA1, sB0, sB1);
    }

    // epilogue: 32x32 C/D layout: col = lane&31, row = (reg&3)+8*(reg>>2)+4*(lane>>5)
#pragma unroll
    for (int mt = 0; mt < 4; mt++) {
        const int rbase = bm0 + wm * 128 + mt * 32 + 4 * h;
        float sx[16];
#pragma unroll
        for (int reg = 0; reg < 16; reg++)
            sx[reg] = scale_x[rbase + (reg & 3) + 8 * (reg >> 2)];
#pragma unroll
        for (int nt = 0; nt < 2; nt++) {
            const int oc = bn0 + wn * 64 + nt * 32 + l31;
            const float sw = scale_w[oc];
            const float bs = bias[oc];
#pragma unroll
            for (int reg = 0; reg < 16; reg++) {
                const int rr = rbase + (reg & 3) + 8 * (reg >> 2);
                out[(size_t)rr * O_DIM + oc] =
                    (float)acc[mt][nt][reg] * sx[reg] * sw + bs;
            }
        }
    }
}

// ---------------------------------------------------------------------------
extern "C" void kernel_launch(void* const* d_in, const int* in_sizes, int n_in,
                              void* d_out, int out_size, void* d_ws, size_t ws_size,
                              hipStream_t stream) {
    const float* x        = (const float*)d_in[0];
    const int*   w_packed = (const int*)d_in[1];
    const float* svd_up   = (const float*)d_in[2];
    const float* svd_down = (const float*)d_in[3];
    const float* scale    = (const float*)d_in[4];
    const float* zp       = (const float*)d_in[5];
    const float* bias     = (const float*)d_in[6];
    float* out = (float*)d_out;

    char* ws = (char*)d_ws;
    char*  w_q     = ws;                                   // 16 MB int8 [O, I]
    char*  x_q     = ws + ((size_t)16 << 20);              // 16 MB int8 [N, I]
    float* scale_w = (float*)(ws + ((size_t)32 << 20));    // 16 KB
    float* scale_x = (float*)(ws + ((size_t)32 << 20) + 16384);  // 16 KB

    prep_kernel<<<W_BLOCKS + N_TOK, 256, 0, stream>>>(
        w_packed, svd_up, svd_down, scale, zp, w_q, scale_w, x, x_q, scale_x);
    gemm_i8_kernel<<<(N_TOK / TBM) * (O_DIM / TBN), 512, 0, stream>>>(
        x_q, w_q, scale_x, scale_w, bias, out);
}

// Round 13
// 240.922 us; speedup vs baseline: 1.0744x; 1.0744x over previous
//
#include <hip/hip_runtime.h>
#include <cstdint>
#include <cstddef>

#define I_DIM 4096
#define O_DIM 4096
#define RNK 32
#define NGRP 64
#define N_TOK 4096

typedef int v4i  __attribute__((ext_vector_type(4)));
typedef int v16i __attribute__((ext_vector_type(16)));

__device__ __forceinline__ int clamp_i8(float v) {
    int q = (int)rintf(v);           // round half to even, matches jnp.round
    q = q < -128 ? -128 : q;
    q = q > 127 ? 127 : q;
    return q;
}

// ---------------------------------------------------------------------------
// prep_kernel = quant_w (blocks [0,1024)) + quant_x (blocks [1024,5120)).
// ---------------------------------------------------------------------------
#define BO 4
#define W_BLOCKS (O_DIM / BO)   // 1024

__device__ __forceinline__ void quant_w_body(
    const int* __restrict__ w_packed, const float* __restrict__ svd_up,
    const float* __restrict__ svd_down, const float* __restrict__ scale,
    const float* __restrict__ zp, char* __restrict__ w_q,
    float* __restrict__ scale_w, int blk)
{
    __shared__ float s_sc[BO][NGRP];
    __shared__ float s_zp[BO][NGRP];
    __shared__ float s_red[BO][4];
    __shared__ float s_sw[BO];

    const int tid = threadIdx.x;
    const int o0 = blk * BO;

    for (int t = tid; t < BO * NGRP; t += 256) {
        s_sc[t >> 6][t & 63] = scale[(size_t)(o0 + (t >> 6)) * NGRP + (t & 63)];
        s_zp[t >> 6][t & 63] = zp[(size_t)(o0 + (t >> 6)) * NGRP + (t & 63)];
    }
    __syncthreads();

    float W[4][BO][4];     // [col-quad jq][row ro][col-in-quad]

    // affine dequant of the int4 values (init)
#pragma unroll
    for (int jq = 0; jq < 4; jq++) {
        const int q = tid + 256 * jq;    // col-quad index, 0..1023
        const int g = q >> 4;            // group (4 cols same group)
#pragma unroll
        for (int ro = 0; ro < BO; ro++) {
            const int2 b2 = *(const int2*)&w_packed[(size_t)(o0 + ro) * (I_DIM / 2) + 2 * q];
            const float sc = s_sc[ro][g], z = s_zp[ro][g];
            W[jq][ro][0] = ((float)(b2.x & 0xF) - z) * sc;
            W[jq][ro][1] = ((float)((b2.x >> 4) & 0xF) - z) * sc;
            W[jq][ro][2] = ((float)(b2.y & 0xF) - z) * sc;
            W[jq][ro][3] = ((float)((b2.y >> 4) & 0xF) - z) * sc;
        }
    }

    // rank-32 SVD correction, r-OUTER; per-element accumulation order is
    // identical to the r-loop order -> bitwise-identical result.
#pragma unroll 2
    for (int r = 0; r < RNK; r++) {
        float u[BO];
#pragma unroll
        for (int ro = 0; ro < BO; ro++)
            u[ro] = svd_up[(size_t)(o0 + ro) * RNK + r];
        float4 d[4];
#pragma unroll
        for (int jq = 0; jq < 4; jq++)
            d[jq] = *(const float4*)&svd_down[(size_t)r * I_DIM + 4 * (tid + 256 * jq)];
#pragma unroll
        for (int jq = 0; jq < 4; jq++)
#pragma unroll
            for (int ro = 0; ro < BO; ro++) {
                W[jq][ro][0] += u[ro] * d[jq].x;
                W[jq][ro][1] += u[ro] * d[jq].y;
                W[jq][ro][2] += u[ro] * d[jq].z;
                W[jq][ro][3] += u[ro] * d[jq].w;
            }
    }

    float vmax[BO];
#pragma unroll
    for (int ro = 0; ro < BO; ro++) vmax[ro] = 0.0f;
#pragma unroll
    for (int jq = 0; jq < 4; jq++)
#pragma unroll
        for (int ro = 0; ro < BO; ro++)
            vmax[ro] = fmaxf(vmax[ro],
                fmaxf(fmaxf(fabsf(W[jq][ro][0]), fabsf(W[jq][ro][1])),
                      fmaxf(fabsf(W[jq][ro][2]), fabsf(W[jq][ro][3]))));

    // block-wide max per row
    const int lane = tid & 63, wv = tid >> 6;
#pragma unroll
    for (int ro = 0; ro < BO; ro++) {
        float m = vmax[ro];
        for (int off = 32; off > 0; off >>= 1)
            m = fmaxf(m, __shfl_down(m, off, 64));
        if (lane == 0) s_red[ro][wv] = m;
    }
    __syncthreads();
    if (tid < BO) {
        const float m = fmaxf(fmaxf(s_red[tid][0], s_red[tid][1]),
                              fmaxf(s_red[tid][2], s_red[tid][3]));
        const float sw = m / 127.0f;
        scale_w[o0 + tid] = sw;
        s_sw[tid] = sw;
    }
    __syncthreads();

    float inv[BO];
#pragma unroll
    for (int ro = 0; ro < BO; ro++) inv[ro] = 1.0f / s_sw[ro];

    // quantize from registers, pack 4 int8 per int store
#pragma unroll
    for (int jq = 0; jq < 4; jq++) {
        const int q = tid + 256 * jq;
#pragma unroll
        for (int ro = 0; ro < BO; ro++) {
            const int q0 = clamp_i8(W[jq][ro][0] * inv[ro]);
            const int q1 = clamp_i8(W[jq][ro][1] * inv[ro]);
            const int q2 = clamp_i8(W[jq][ro][2] * inv[ro]);
            const int q3 = clamp_i8(W[jq][ro][3] * inv[ro]);
            ((int*)w_q)[(size_t)(o0 + ro) * (I_DIM / 4) + q] =
                (q0 & 0xFF) | ((q1 & 0xFF) << 8) | ((q2 & 0xFF) << 16) | ((q3 & 0xFF) << 24);
        }
    }
}

__device__ __forceinline__ void quant_x_body(
    const float* __restrict__ x, char* __restrict__ x_q,
    float* __restrict__ scale_x, int n)
{
    const int tid = threadIdx.x;
    const float4* xr = (const float4*)(x + (size_t)n * I_DIM);
    float4 v[4];
    float m = 0.0f;
#pragma unroll
    for (int j = 0; j < 4; j++) {
        v[j] = xr[tid + 256 * j];
        m = fmaxf(m, fmaxf(fmaxf(fabsf(v[j].x), fabsf(v[j].y)),
                           fmaxf(fabsf(v[j].z), fabsf(v[j].w))));
    }
    __shared__ float s_red[4];
    __shared__ float s_sx;
    for (int off = 32; off > 0; off >>= 1)
        m = fmaxf(m, __shfl_down(m, off, 64));
    if ((tid & 63) == 0) s_red[tid >> 6] = m;
    __syncthreads();
    if (tid == 0) {
        const float mm = fmaxf(fmaxf(s_red[0], s_red[1]),
                               fmaxf(s_red[2], s_red[3]));
        const float sx = mm / 127.0f;
        scale_x[n] = sx;
        s_sx = sx;
    }
    __syncthreads();
    const float sx = s_sx;
    int* outw = (int*)(x_q + (size_t)n * I_DIM);
#pragma unroll
    for (int j = 0; j < 4; j++) {
        const int q0 = clamp_i8(v[j].x / sx);
        const int q1 = clamp_i8(v[j].y / sx);
        const int q2 = clamp_i8(v[j].z / sx);
        const int q3 = clamp_i8(v[j].w / sx);
        outw[tid + 256 * j] =
            (q0 & 0xFF) | ((q1 & 0xFF) << 8) | ((q2 & 0xFF) << 16) | ((q3 & 0xFF) << 24);
    }
}

__global__ __launch_bounds__(256, 4) void prep_kernel(
    const int* __restrict__ w_packed, const float* __restrict__ svd_up,
    const float* __restrict__ svd_down, const float* __restrict__ scale,
    const float* __restrict__ zp, char* __restrict__ w_q,
    float* __restrict__ scale_w,
    const float* __restrict__ x, char* __restrict__ x_q,
    float* __restrict__ scale_x)
{
    if (blockIdx.x < W_BLOCKS)
        quant_w_body(w_packed, svd_up, svd_down, scale, zp, w_q, scale_w, blockIdx.x);
    else
        quant_x_body(x, x_q, scale_x, blockIdx.x - W_BLOCKS);
}

// ---------------------------------------------------------------------------
// Kernel 2: int8 GEMM, 256x256 tile, BK=128 bytes, mfma_i32_32x32x32_i8.
//
// Round-12 design (resubmitted through infra flake): BK=128 dissolves the
// conflict-vs-staging-width tradeoff.
// Conflict ledger (r4/r6/r10/r11): bank spreading for column reads =
// row-parity bit + bits the swizzle injects into the column offset.
// TBK=64 has only 4 16B-chunks/row -> 2 bits -> 4-way floor (+8cyc/b128,
// r4). All zero-conflict fixes (8B granule) cost more instructions than
// the conflicts (r6 4B staging -38%; r11 b64 reads + ds_write -26%).
// TBK=128 has 8 chunks/row -> 3 swizzle bits: kc = (c&7)^(row&7) spreads
// 8 consecutive rows over all 8 bank-quads -> a b128's 16-lane phase is
// 2-way = FREE (m136: 1.02x), with 16B global_load_lds staging and b128
// reads intact (m201's st_16x32 geometry). Bonus: 32 barriers instead of
// 64 -> sync overhead amortizes 2x.
// Structure otherwise = r4 (best, 77.8us): 512 thr, 2Mx4N waves (128x64),
// reg-double-buffered frags (a0/b0 vs a1/b1 alternate over 4 phases),
// ONE vmcnt(0)+lgkmcnt(0)+barrier per K-tile (loads issued ~2000cyc
// earlier -> drain ~free; lgkmcnt(0) before barrier makes distance-1
// 2-buffer recycling WAR-safe), setprio, XCD swizzle.
// LDS: 2 buffers x (A 32KB + B 32KB) = 128KB -> 1 block/CU (unchanged;
// m132's BK=128 occupancy cliff doesn't apply at 1 block/CU).
// ---------------------------------------------------------------------------
#define TBM 256
#define TBN 256
#define TBK 128
#define NKT (I_DIM / TBK)   // 32 K-tiles

__device__ __forceinline__ void stage_tile(const char* __restrict__ src, int row0,
                                           int t, char* lds_mat, int tid)
{
#pragma unroll
    for (int uu = 0; uu < 4; uu++) {
        const int c = tid + uu * 512;            // 16B slot, 0..2047
        const int row = c >> 3;                  // 256 rows, 8 chunks each
        const int kc = (c & 7) ^ (row & 7);      // 3-bit pre-swizzle
        const char* g = src + (size_t)(row0 + row) * I_DIM + t * TBK + kc * 16;
        __builtin_amdgcn_global_load_lds(
            (const __attribute__((address_space(1))) unsigned int*)g,
            (__attribute__((address_space(3))) unsigned int*)(lds_mat + c * 16),
            16, 0, 0);
    }
}

// read fragment set (AF,BF) for phase P (0..3) from buffer base BUF
#define READ_FRAGS(AF, BF, BUF, P) do {                                     \
    char* Ac_ = (BUF);                                                      \
    char* Bc_ = (BUF) + 32768;                                              \
    _Pragma("unroll")                                                       \
    for (int mt = 0; mt < 4; mt++) {                                        \
        const int row = wm * 128 + mt * 32 + l31;                           \
        const int kc = ((P) * 2 + h) ^ (row & 7);                           \
        AF[mt] = *(const v4i*)(Ac_ + row * TBK + kc * 16);                  \
    }                                                                       \
    _Pragma("unroll")                                                       \
    for (int nt = 0; nt < 2; nt++) {                                        \
        const int row = wn * 64 + nt * 32 + l31;                            \
        const int kc = ((P) * 2 + h) ^ (row & 7);                           \
        BF[nt] = *(const v4i*)(Bc_ + row * TBK + kc * 16);                  \
    }                                                                       \
} while (0)

#define MFMA_CLUSTER(AF, BF) do {                                           \
    __builtin_amdgcn_s_setprio(1);                                          \
    _Pragma("unroll")                                                       \
    for (int mt = 0; mt < 4; mt++)                                          \
        _Pragma("unroll")                                                   \
        for (int nt = 0; nt < 2; nt++)                                      \
            acc[mt][nt] = __builtin_amdgcn_mfma_i32_32x32x32_i8(            \
                AF[mt], BF[nt], acc[mt][nt], 0, 0, 0);                      \
    __builtin_amdgcn_s_setprio(0);                                          \
} while (0)

__global__ __launch_bounds__(512, 1) void gemm_i8_kernel(
    const char* __restrict__ x_q, const char* __restrict__ w_q,
    const float* __restrict__ scale_x, const float* __restrict__ scale_w,
    const float* __restrict__ bias, float* __restrict__ out)
{
    __shared__ v4i smem4[2 * 4096];     // 2 bufs x {A 32KB, B 32KB} = 128 KB
    char* lds = (char*)smem4;

    const int tid = threadIdx.x;
    // XCD-aware swizzle: xcd = id&7 owns bn bands [xcd*2, xcd*2+2);
    // s&15 sweeps bm within the band (B tile L2-resident per XCD).
    const int id = blockIdx.x;
    const int xcd = id & 7;
    const int s = id >> 3;                  // 0..31
    const int bm0 = (s & 15) * TBM;
    const int bn0 = (xcd * 2 + (s >> 4)) * TBN;

    const int lane = tid & 63, wv = tid >> 6;
    const int wm = wv >> 2, wn = wv & 3;    // 2M x 4N waves, 128x64 each
    const int l31 = lane & 31, h = lane >> 5;

    v16i acc[4][2];
#pragma unroll
    for (int mt = 0; mt < 4; mt++)
#pragma unroll
        for (int nt = 0; nt < 2; nt++)
            acc[mt][nt] = (v16i)(0);

    v4i a0[4], b0[2], a1[4], b1[2];     // two named frag sets (static idx)

    // prologue: stage tile 0 into buf0, drain, read P0 frags
    stage_tile(x_q, bm0, 0, lds, tid);
    stage_tile(w_q, bn0, 0, lds + 32768, tid);
    asm volatile("s_waitcnt vmcnt(0)" ::: "memory");
    asm volatile("s_barrier" ::: "memory");
    READ_FRAGS(a0, b0, lds, 0);

    for (int t = 0; t < NKT; ++t) {
        char* bufc = lds + (t & 1) * 65536;
        char* bufn = lds + ((t + 1) & 1) * 65536;
        const bool pf = (t + 1 < NKT);

        // phase 0..3 of tile t; stage t+1 interleaved (A early, B mid) so
        // its HBM latency hides under ~2300 cyc of MFMA before the drain.
        if (pf) stage_tile(x_q, bm0, t + 1, bufn, tid);
        READ_FRAGS(a1, b1, bufc, 1);
        MFMA_CLUSTER(a0, b0);
        READ_FRAGS(a0, b0, bufc, 2);
        MFMA_CLUSTER(a1, b1);
        if (pf) stage_tile(w_q, bn0, t + 1, bufn + 32768, tid);
        READ_FRAGS(a1, b1, bufc, 3);
        MFMA_CLUSTER(a0, b0);

        if (t < NKT - 1) {
            // publish tile t+1 (vmcnt) + drain own reads of bufc (lgkm) so
            // the next iteration may overwrite it (WAR-safe), then barrier;
            // start next tile's P0 reads, drained under MFMA(P3).
            asm volatile("s_waitcnt vmcnt(0)" ::: "memory");
            asm volatile("s_waitcnt lgkmcnt(0)" ::: "memory");
            asm volatile("s_barrier" ::: "memory");
            READ_FRAGS(a0, b0, bufn, 0);
        }
        MFMA_CLUSTER(a1, b1);
    }

    // epilogue: 32x32 C/D layout: col = lane&31, row = (reg&3)+8*(reg>>2)+4*(lane>>5)
#pragma unroll
    for (int mt = 0; mt < 4; mt++) {
        const int rbase = bm0 + wm * 128 + mt * 32 + 4 * h;
        float sx[16];
#pragma unroll
        for (int reg = 0; reg < 16; reg++)
            sx[reg] = scale_x[rbase + (reg & 3) + 8 * (reg >> 2)];
#pragma unroll
        for (int nt = 0; nt < 2; nt++) {
            const int oc = bn0 + wn * 64 + nt * 32 + l31;
            const float sw = scale_w[oc];
            const float bs = bias[oc];
#pragma unroll
            for (int reg = 0; reg < 16; reg++) {
                const int rr = rbase + (reg & 3) + 8 * (reg >> 2);
                out[(size_t)rr * O_DIM + oc] =
                    (float)acc[mt][nt][reg] * sx[reg] * sw + bs;
            }
        }
    }
}

// ---------------------------------------------------------------------------
extern "C" void kernel_launch(void* const* d_in, const int* in_sizes, int n_in,
                              void* d_out, int out_size, void* d_ws, size_t ws_size,
                              hipStream_t stream) {
    const float* x        = (const float*)d_in[0];
    const int*   w_packed = (const int*)d_in[1];
    const float* svd_up   = (const float*)d_in[2];
    const float* svd_down = (const float*)d_in[3];
    const float* scale    = (const float*)d_in[4];
    const float* zp       = (const float*)d_in[5];
    const float* bias     = (const float*)d_in[6];
    float* out = (float*)d_out;

    char* ws = (char*)d_ws;
    char*  w_q     = ws;                                   // 16 MB int8 [O, I]
    char*  x_q     = ws + ((size_t)16 << 20);              // 16 MB int8 [N, I]
    float* scale_w = (float*)(ws + ((size_t)32 << 20));    // 16 KB
    float* scale_x = (float*)(ws + ((size_t)32 << 20) + 16384);  // 16 KB

    prep_kernel<<<W_BLOCKS + N_TOK, 256, 0, stream>>>(
        w_packed, svd_up, svd_down, scale, zp, w_q, scale_w, x, x_q, scale_x);
    gemm_i8_kernel<<<(N_TOK / TBM) * (O_DIM / TBN), 512, 0, stream>>>(
        x_q, w_q, scale_x, scale_w, bias, out);
}